// Round 3
// baseline (253.893 us; speedup 1.0000x reference)
//
#include <hip/hip_runtime.h>
#include <math.h>

// ---- Problem constants (derived from the reference) ----
// IN0 dim = 120, HID1 dim = 180, K1 = 64*180 = 11520
// out layout: x_out [64,180] | grid1 [64,K1,72] | radii [512]
#define K1        11520
#define XDIM      180
#define NSP       64
#define NG        72
#define OUT1_OFF  11520
#define OUT2_OFF  (11520 + (size_t)NSP * K1 * NG)

#define INV_S32 0.17677669529663687f  // 1/sqrt(32)
#define INV_S8  0.35355339059327373f  // 1/sqrt(8)
#define INV_S16 0.25f                 // 1/sqrt(16)
#define INV_S64 0.125f                // 1/sqrt(64)

// ---------------------------------------------------------------------------
// Single fused kernel. Grid: (45, 64) blocks x 256 threads.
// Each block: spatial point s = blockIdx.y, k-tile [blockIdx.x*256, +256).
//
// Phase 0: redundantly compute xs[180] (= x_out row s) from x + small weights
//          (~6.5K MACs, trivial vs the 72 KB this block stores). Threads
//          64..135 build the 8 non-trivial Y rows (row 0 is all-ones, folded
//          into the accumulator init). bx==0 blocks also write x_out + radii.
// Phase 1: thread t computes the 9 coeffs for k = bx*256+t (coalesced weight
//          column loads), stages them LDS-padded to 12 (float4-readable).
// Phase 2: j-pair loop. g has period 9 in j (1024 mod 72 = 16; 16*9 % 72 = 0),
//          so one 8x float4 Y fragment serves stores j and j+9 (kk2 = kk+128).
//          Per wave-j: 8 b128 (Y) + 2*(2 b128 + 1 b32) (coeff) -> 2 coalesced
//          1KB stores. LDS-pipe ~156 cyc per 204 HBM cyc -> write-bound.
//
// Dead inputs (zero-propagation through eq_linear): w2b0_* (grid0 unused),
// w1b1_0o / w1b1_1e / w1b1_2o (multiply exact zeros).
// ---------------------------------------------------------------------------
__global__ __launch_bounds__(256) void up_fused_kernel(
    const float* __restrict__ x,          // [64,120]
    const float* __restrict__ w1b0_0e,    // [32,64]
    const float* __restrict__ w1b0_1o,    // [16,16]
    const float* __restrict__ w1b0_2e,    // [8,16]
    const float* __restrict__ w1b1_0e,    // [64,32]
    const float* __restrict__ w1b1_1o,    // [16,8]
    const float* __restrict__ w1b1_2e,    // [16,8]
    const float* __restrict__ w2b1_0e,    // [32,K1]
    const float* __restrict__ w2b1_1o,    // [8,K1]
    const float* __restrict__ w2b1_2e,    // [8,K1]
    float* __restrict__ out)
{
    __shared__ float xin[120];
    __shared__ float x1_0e[64];
    __shared__ float x1_2e[80];        // (16,5): [i*5+m]
    __shared__ float x1_1o[48];        // (16,3): [i*3+m]
    __shared__ float xs[XDIM];
    __shared__ float Yl[8 * NG];       // rows cc=1..8 (row 0 == 1.0 skipped)
    __shared__ float coeff[256 * 12];  // 9 coeffs padded to 12 -> float4 reads

    const int t = threadIdx.x;
    const int s = blockIdx.y;

    // ---- Phase 0a: stage xin | build Y | zero xs (disjoint thread ranges)
    if (t < 64) {
        xin[t] = x[s * 120 + t];
        if (t + 64 < 120) xin[t + 64] = x[s * 120 + t + 64];
    } else if (t < 136) {
        int g = t - 64;                 // 0..71
        int bi = g / 12, ai = g % 12;
        float bb = (bi + 0.5f) * (float)(M_PI / 6.0);
        float aa = (float)ai * (float)(M_PI / 6.0);   // 2*pi/12
        float sb = sinf(bb), cb = cosf(bb);
        float sa = sinf(aa), ca = cosf(aa);
        float sx = sb * ca, sy = sb * sa, sz = cb;
        const float s3  = 1.7320508075688772f;
        const float s15 = 3.872983346207417f;
        const float s5  = 2.23606797749979f;
        Yl[0 * NG + g] = s3 * sx;
        Yl[1 * NG + g] = s3 * sy;
        Yl[2 * NG + g] = s3 * sz;
        Yl[3 * NG + g] = s15 * sx * sy;
        Yl[4 * NG + g] = s15 * sy * sz;
        Yl[5 * NG + g] = 0.5f * s5 * (3.0f * sz * sz - 1.0f);
        Yl[6 * NG + g] = s15 * sx * sz;
        Yl[7 * NG + g] = 0.5f * s15 * (sx * sx - sy * sy);
    } else {
        for (int f = t - 136; f < XDIM; f += 120) xs[f] = 0.0f;
    }
    __syncthreads();

    // ---- Phase 0b: block-0 equivariant linear (HID0 live segments only)
    if (t < 64) {
        float acc = 0.0f;
        #pragma unroll
        for (int j = 0; j < 32; ++j) acc += xin[j] * w1b0_0e[j * 64 + t];
        x1_0e[t] = acc * INV_S32;
    } else if (t < 144) {
        int e = t - 64, i = e / 5, m = e % 5;   // 80 elements
        float acc = 0.0f;
        #pragma unroll
        for (int j = 0; j < 8; ++j) acc += xin[80 + j * 5 + m] * w1b0_2e[j * 16 + i];
        x1_2e[e] = acc * INV_S8;
    } else if (t < 192) {
        int e = t - 144, i = e / 3, m = e % 3;  // 48 elements
        float acc = 0.0f;
        #pragma unroll
        for (int j = 0; j < 16; ++j) acc += xin[32 + j * 3 + m] * w1b0_1o[j * 16 + i];
        x1_1o[e] = acc * INV_S16;
    }
    __syncthreads();

    // ---- Phase 0c: block-1 equivariant linear -> xs (x_out row)
    if (t < 32) {
        float acc = 0.0f;
        #pragma unroll
        for (int i = 0; i < 64; ++i) acc += x1_0e[i] * w1b1_0e[i * 32 + t];
        xs[t] = acc * INV_S64;
    } else if (t < 72) {
        int e = t - 32, o = e / 5, m = e % 5;   // 40 elements @ [96,136)
        float acc = 0.0f;
        #pragma unroll
        for (int i = 0; i < 16; ++i) acc += x1_2e[i * 5 + m] * w1b1_2e[i * 8 + o];
        xs[96 + e] = acc * INV_S16;
    } else if (t < 96) {
        int e = t - 72, o = e / 3, m = e % 3;   // 24 elements @ [136,160)
        float acc = 0.0f;
        #pragma unroll
        for (int i = 0; i < 16; ++i) acc += x1_1o[i * 3 + m] * w1b1_1o[i * 8 + o];
        xs[136 + e] = acc * INV_S16;
    }
    __syncthreads();

    // x_out + radii (constant 27: every fine point is sqrt(0.75) from its
    // coarse center; nearest bin of linspace(0,2,64) is 27), one block per s.
    if (blockIdx.x == 0) {
        if (t < XDIM) out[(size_t)s * XDIM + t] = xs[t];
        else if (t < XDIM + 8) out[OUT2_OFF + (size_t)s * 8 + (t - XDIM)] = 27.0f;
    }

    // ---- Phase 1: 9 coefficients for k = bx*256 + t; stage padded to 12
    {
        const int k = blockIdx.x * 256 + t;
        float c[9];
        float acc = 0.0f;
        #pragma unroll
        for (int i = 0; i < 32; ++i) acc += xs[i] * w2b1_0e[i * K1 + k];
        c[0] = acc * INV_S32;
        #pragma unroll
        for (int m = 0; m < 3; ++m) {
            acc = 0.0f;
            #pragma unroll
            for (int i = 0; i < 8; ++i) acc += xs[136 + i * 3 + m] * w2b1_1o[i * K1 + k];
            c[1 + m] = acc * INV_S8;
        }
        #pragma unroll
        for (int m = 0; m < 5; ++m) {
            acc = 0.0f;
            #pragma unroll
            for (int i = 0; i < 8; ++i) acc += xs[96 + i * 5 + m] * w2b1_2e[i * K1 + k];
            c[4 + m] = acc * INV_S8;
        }
        *(float4*)&coeff[t * 12]     = make_float4(c[0], c[1], c[2], c[3]);
        *(float4*)&coeff[t * 12 + 4] = make_float4(c[4], c[5], c[6], c[7]);
        coeff[t * 12 + 8] = c[8];
    }
    __syncthreads();

    // ---- Phase 2: paired stores. Block tile = 256k x 72g = 4608 float4.
    // float4 index f = t + j*256 (j<9) and f+2304; same g, kk2 = kk+128.
    float* outbase = out + OUT1_OFF
                   + ((size_t)s * K1 + (size_t)blockIdx.x * 256) * NG;
    #pragma unroll
    for (int j = 0; j < 9; ++j) {
        const int e  = (t + j * 256) * 4;   // element offset in [0, 9216)
        const int kk = e / NG;              // local k in [0,128)
        const int g  = e - kk * NG;         // multiple of 4

        float4 Y1 = *(const float4*)&Yl[0 * NG + g];
        float4 Y2 = *(const float4*)&Yl[1 * NG + g];
        float4 Y3 = *(const float4*)&Yl[2 * NG + g];
        float4 Y4 = *(const float4*)&Yl[3 * NG + g];
        float4 Y5 = *(const float4*)&Yl[4 * NG + g];
        float4 Y6 = *(const float4*)&Yl[5 * NG + g];
        float4 Y7 = *(const float4*)&Yl[6 * NG + g];
        float4 Y8 = *(const float4*)&Yl[7 * NG + g];

        #pragma unroll
        for (int p = 0; p < 2; ++p) {
            const int kp = kk + p * 128;
            float4 ca = *(const float4*)&coeff[kp * 12];
            float4 cb = *(const float4*)&coeff[kp * 12 + 4];
            float  c8 = coeff[kp * 12 + 8];
            float4 acc;
            acc.x = ca.x; acc.y = ca.x; acc.z = ca.x; acc.w = ca.x;  // Y row 0 == 1
            acc.x += ca.y * Y1.x; acc.y += ca.y * Y1.y; acc.z += ca.y * Y1.z; acc.w += ca.y * Y1.w;
            acc.x += ca.z * Y2.x; acc.y += ca.z * Y2.y; acc.z += ca.z * Y2.z; acc.w += ca.z * Y2.w;
            acc.x += ca.w * Y3.x; acc.y += ca.w * Y3.y; acc.z += ca.w * Y3.z; acc.w += ca.w * Y3.w;
            acc.x += cb.x * Y4.x; acc.y += cb.x * Y4.y; acc.z += cb.x * Y4.z; acc.w += cb.x * Y4.w;
            acc.x += cb.y * Y5.x; acc.y += cb.y * Y5.y; acc.z += cb.y * Y5.z; acc.w += cb.y * Y5.w;
            acc.x += cb.z * Y6.x; acc.y += cb.z * Y6.y; acc.z += cb.z * Y6.z; acc.w += cb.z * Y6.w;
            acc.x += cb.w * Y7.x; acc.y += cb.w * Y7.y; acc.z += cb.w * Y7.z; acc.w += cb.w * Y7.w;
            acc.x += c8  * Y8.x; acc.y += c8  * Y8.y; acc.z += c8  * Y8.z; acc.w += c8  * Y8.w;
            *(float4*)(outbase + e + p * 9216) = acc;
        }
    }
}

extern "C" void kernel_launch(void* const* d_in, const int* in_sizes, int n_in,
                              void* d_out, int out_size, void* d_ws, size_t ws_size,
                              hipStream_t stream) {
    const float* x        = (const float*)d_in[0];
    const float* w1b0_0e  = (const float*)d_in[1];
    const float* w1b0_1o  = (const float*)d_in[2];
    const float* w1b0_2e  = (const float*)d_in[3];
    // d_in[4..6] = w2b0_* : dead (grid0/sh0 unused by reference outputs)
    const float* w1b1_0e  = (const float*)d_in[7];
    // d_in[8] w1b1_0o, d_in[9] w1b1_1e, d_in[12] w1b1_2o: multiply exact zeros
    const float* w1b1_1o  = (const float*)d_in[10];
    const float* w1b1_2e  = (const float*)d_in[11];
    const float* w2b1_0e  = (const float*)d_in[13];
    const float* w2b1_1o  = (const float*)d_in[14];
    const float* w2b1_2e  = (const float*)d_in[15];
    float* out = (float*)d_out;

    up_fused_kernel<<<dim3(K1 / 256, NSP), dim3(256), 0, stream>>>(
        x, w1b0_0e, w1b0_1o, w1b0_2e, w1b1_0e, w1b1_1o, w1b1_2e,
        w2b1_0e, w2b1_1o, w2b1_2e, out);
}